// Round 6
// baseline (265.351 us; speedup 1.0000x reference)
//
#include <hip/hip_runtime.h>

typedef __attribute__((ext_vector_type(8))) short short8;
typedef __attribute__((ext_vector_type(4))) float f32x4;
typedef __attribute__((ext_vector_type(2))) float f32x2;

#define SEQ 2048
#define BAT 8
#define DIM 512
#define RSQRT_D 0.044194173824159216f  // 1/sqrt(512)

__device__ __forceinline__ unsigned short f2bf(float x) {
  union { float f; unsigned u; } v; v.f = x;
  unsigned r = (v.u + 0x7FFFu + ((v.u >> 16) & 1u)) >> 16;  // RNE
  return (unsigned short)r;
}

__device__ __forceinline__ unsigned char f2fp8(float x) {
  return (unsigned char)(__builtin_amdgcn_cvt_pk_fp8_f32(x, x, 0, false) & 0xFF);
}

// async 16B global -> LDS. lds base wave-uniform; HW adds lane*16.
__device__ __forceinline__ void gload_lds16(const void* g, void* lds_base) {
  __builtin_amdgcn_global_load_lds(
      (const __attribute__((address_space(1))) unsigned int*)g,
      (__attribute__((address_space(3))) unsigned int*)lds_base,
      16, 0, 0);
}

// ---------------------------------------------------------------------------
// Kernel 1: fused pack. blocks x<4096: transpose feats (S,B,D) f32 ->
// (B,S,D) bf16 + overlap dot (y = src/tgt). blocks >=4096: y==0 -> cast
// Wq/Wk -> bf16; y==1 -> pack xyz -> (B,S,4) f32. grid = (4352, 2).
// ---------------------------------------------------------------------------
__global__ __launch_bounds__(256) void k_pack(
    const float* __restrict__ src, const float* __restrict__ tgt,
    const float* __restrict__ Wc, const float* __restrict__ bc,
    const float* __restrict__ sxyz, const float* __restrict__ txyz,
    const float* __restrict__ Wq, const float* __restrict__ Wk,
    unsigned short* __restrict__ srcT, unsigned short* __restrict__ tgtT,
    float4* __restrict__ Vsrc, float4* __restrict__ Vtgt,
    unsigned short* __restrict__ Wqb, unsigned short* __restrict__ Wkb,
    float* __restrict__ out) {
  int which = blockIdx.y;
  if (blockIdx.x >= 4096) {
    int e = (blockIdx.x - 4096) * 256 + threadIdx.x;   // 0..65535
    if (which == 0) {
      // Wq/Wk f32 -> bf16, 65536 chunks of 8
      int wsel = e >> 15, j = e & 32767;
      const float* wp = (wsel ? Wk : Wq) + (size_t)j * 8;
      unsigned short* o = wsel ? Wkb : Wqb;
      float4 f0 = *(const float4*)wp, f1 = *(const float4*)(wp + 4);
      uint4 pk;
      pk.x = (unsigned)f2bf(f0.x) | ((unsigned)f2bf(f0.y) << 16);
      pk.y = (unsigned)f2bf(f0.z) | ((unsigned)f2bf(f0.w) << 16);
      pk.z = (unsigned)f2bf(f1.x) | ((unsigned)f2bf(f1.y) << 16);
      pk.w = (unsigned)f2bf(f1.z) | ((unsigned)f2bf(f1.w) << 16);
      *(uint4*)(o + (size_t)j * 8) = pk;
    } else if (e < 32768) {
      int wsel = e >> 14, id = e & 16383;
      int s = id >> 3, b = id & 7;
      const float* xyz = (wsel ? txyz : sxyz) + (size_t)id * 3;
      float4 v = make_float4(xyz[0], xyz[1], xyz[2], 0.f);
      (wsel ? Vtgt : Vsrc)[b * SEQ + s] = v;
    }
    return;
  }
  int w = threadIdx.x >> 6, lane = threadIdx.x & 63;
  int row = blockIdx.x * 4 + w;            // row = s*B + b
  const float* in = (which ? tgt : src) + (size_t)row * DIM;
  unsigned short* T = which ? tgtT : srcT;
  int s = row >> 3, b = row & 7;

  const float4* in4 = (const float4*)in;
  float4 f0 = in4[lane * 2], f1 = in4[lane * 2 + 1];

  uint4 pk;
  pk.x = (unsigned)f2bf(f0.x) | ((unsigned)f2bf(f0.y) << 16);
  pk.y = (unsigned)f2bf(f0.z) | ((unsigned)f2bf(f0.w) << 16);
  pk.z = (unsigned)f2bf(f1.x) | ((unsigned)f2bf(f1.y) << 16);
  pk.w = (unsigned)f2bf(f1.z) | ((unsigned)f2bf(f1.w) << 16);
  *(uint4*)(T + ((size_t)(b * SEQ + s) * DIM + lane * 8)) = pk;

  const float4* wc4 = (const float4*)Wc;
  float4 w0 = wc4[lane * 2], w1 = wc4[lane * 2 + 1];
  float d = f0.x * w0.x + f0.y * w0.y + f0.z * w0.z + f0.w * w0.w +
            f1.x * w1.x + f1.y * w1.y + f1.z * w1.z + f1.w * w1.w;
  for (int o = 32; o; o >>= 1) d += __shfl_xor(d, o);
  if (lane == 0) {
    int base = which ? (SEQ * BAT * 6 + SEQ * BAT) : (SEQ * BAT * 6);
    out[base + row] = d + bc[0];
  }
}

// ---------------------------------------------------------------------------
// Kernel 2: projection GEMM, fp8-e4m3 output, UNSCALED (1/sqrt(D) in attn).
// Q linear; K with bank-free swizzle baked into the global byte layout:
//   byte (row,d) at row*512 + ((d>>3 ^ (row&15))<<3) + (d&7)
// XCD grouping: the 16 blocks (4 n x 4 z) sharing one m-tile are consecutive
// on one XCD (id%8) -> A-tile L2-fetched once per XCD; W L2-resident.
// grid = 2048 x 1D, block = 256.
// ---------------------------------------------------------------------------
__global__ __launch_bounds__(256) void k_proj(
    const unsigned short* __restrict__ srcT, const unsigned short* __restrict__ tgtT,
    const unsigned short* __restrict__ Wqb, const unsigned short* __restrict__ Wkb,
    const float* __restrict__ bq, const float* __restrict__ bk,
    unsigned char* __restrict__ Qsrc, unsigned char* __restrict__ Ktgt,
    unsigned char* __restrict__ Qtgt, unsigned char* __restrict__ Ksrc) {
  __shared__ __align__(16) char at[16384];   // 128 rows x 128B (64 bf16)
  __shared__ __align__(16) char bt[16384];
  int id = blockIdx.x;                 // 0..2047
  int x = id & 7, t = id >> 3;         // XCD = x (heuristic)
  int m = x * 16 + (t >> 4);           // 0..127, 16 consecutive blocks share m
  int inner = t & 15;
  int n = inner & 3, z = inner >> 2;
  bool isQ = (z == 0 || z == 2);
  const unsigned short* A = (z == 0 || z == 3) ? srcT : tgtT;
  const unsigned short* W = isQ ? Wqb : Wkb;
  const float* bias = isQ ? bq : bk;
  unsigned char* O = z == 0 ? Qsrc : z == 1 ? Ktgt : z == 2 ? Qtgt : Ksrc;

  int m0 = m * 128, n0 = n * 128;
  int tid = threadIdx.x, w = tid >> 6, lane = tid & 63;
  int ln = lane & 15, quad = lane >> 4;
  int moff = (w & 1) * 64, noff = (w >> 1) * 64;

  f32x4 acc[4][4];
  f32x4 zero = {0.f, 0.f, 0.f, 0.f};
  for (int mi = 0; mi < 4; ++mi)
    for (int ni = 0; ni < 4; ++ni) acc[mi][ni] = zero;

  for (int kb = 0; kb < DIM; kb += 64) {
    #pragma unroll
    for (int it = 0; it < 4; ++it) {
      int rbase = w * 32 + it * 8;
      int r = rbase + (lane >> 3);
      int c = (lane & 7) ^ (r & 7);
      gload_lds16(A + ((size_t)(m0 + r) * DIM + kb + c * 8), &at[rbase * 128]);
      gload_lds16(W + ((size_t)(n0 + r) * DIM + kb + c * 8), &bt[rbase * 128]);
    }
    __syncthreads();
    #pragma unroll
    for (int ks = 0; ks < 2; ++ks) {
      short8 afr[4], bfr[4];
      #pragma unroll
      for (int mi = 0; mi < 4; ++mi) {
        int r = moff + mi * 16 + ln;
        int p = (ks * 4 + quad) ^ (r & 7);
        afr[mi] = *(const short8*)(&at[r * 128 + p * 16]);
      }
      #pragma unroll
      for (int ni = 0; ni < 4; ++ni) {
        int r = noff + ni * 16 + ln;
        int p = (ks * 4 + quad) ^ (r & 7);
        bfr[ni] = *(const short8*)(&bt[r * 128 + p * 16]);
      }
      #pragma unroll
      for (int mi = 0; mi < 4; ++mi)
        #pragma unroll
        for (int ni = 0; ni < 4; ++ni)
          acc[mi][ni] = __builtin_amdgcn_mfma_f32_16x16x32_bf16(afr[mi], bfr[ni], acc[mi][ni], 0, 0, 0);
    }
    __syncthreads();
  }

  for (int ni = 0; ni < 4; ++ni) {
    int n_g = n0 + noff + ni * 16 + ln;
    float bv = bias[n_g];
    for (int mi = 0; mi < 4; ++mi) {
      int m_g = m0 + moff + mi * 16 + quad * 4;
      for (int r = 0; r < 4; ++r) {
        float v = acc[mi][ni][r] + bv;
        int row = m_g + r;
        size_t pos;
        if (isQ) pos = (size_t)row * DIM + n_g;
        else     pos = (size_t)row * DIM + ((((n_g >> 3) ^ (row & 15)) << 3) | (n_g & 7));
        O[pos] = f2fp8(v);
      }
    }
  }
}

// ---------------------------------------------------------------------------
// Kernel 3: flash attention, fp8 scores, split-K x4, no-max softmax.
// K-tiles 32 keys x 512 B double-buffered (global_load_lds identity copies,
// swizzle pre-baked in K's global layout). V from global (L2-hot, 128 KB).
// Packed-f32 (v_pk_fma) softmax/PV accumulators; validity mask only in the
// final partial tile (wave-uniform branch). LDS = 32 KB -> 5 blocks/CU.
// XCD grouping: all 128 blocks of a (dir,b) on one XCD. grid = 2048, blk 256.
// ---------------------------------------------------------------------------
__global__ __launch_bounds__(256) void k_attn(
    const unsigned char* __restrict__ Qsrc, const unsigned char* __restrict__ Ktgt,
    const unsigned char* __restrict__ Qtgt, const unsigned char* __restrict__ Ksrc,
    const float4* __restrict__ Vsrc, const float4* __restrict__ Vtgt,
    const int* __restrict__ src_lens, const int* __restrict__ tgt_lens,
    float4* __restrict__ part) {
  __shared__ __align__(16) char klds[32768];   // 2 x (32 keys x 512 B)
  int id = blockIdx.x;                 // 0..2047
  int x = id & 7, j = id >> 3;         // XCD = x (heuristic)
  int group = (j >> 7) * 8 + x;        // 0..15 = dir*8+b, one XCD per group
  int dir = group >> 3, b = group & 7;
  int inner = j & 127;
  int chunk = inner >> 5, qb = inner & 31;

  const unsigned char* Q = dir ? Qtgt : Qsrc;
  const unsigned char* K = dir ? Ksrc : Ktgt;
  const float4* V = dir ? Vsrc : Vtgt;
  int len = (dir ? src_lens : tgt_lens)[b];
  int k0g = chunk * 512;
  int kend = min(len, k0g + 512);      // len >= 1792 so kend > k0g always
  int nk = kend - k0g;                 // 1..512
  int nblk = (nk + 31) >> 5;
  bool tail = (nk & 31) != 0;

  int tid = threadIdx.x, w = tid >> 6, lane = tid & 63;
  int ln = lane & 15, quad = lane >> 4;
  int q0 = qb * 64 + w * 16;

  // Q fp8 A-frags, full D: 16 x 8 B = 32 VGPRs. A[m=ln][k=quad*8+j].
  long af[16];
  {
    const unsigned char* qrow = Q + (size_t)(b * SEQ + q0 + ln) * DIM + quad * 8;
    #pragma unroll
    for (int kk = 0; kk < 16; ++kk)
      af[kk] = *(const long*)(qrow + kk * 32);
  }

  f32x2 l2[4], Ox2[4], Oy2[4], Oz2[4];
  f32x2 z2 = {0.f, 0.f};
  #pragma unroll
  for (int r = 0; r < 4; ++r) { l2[r] = z2; Ox2[r] = z2; Oy2[r] = z2; Oz2[r] = z2; }

  const unsigned char* kchunk = K + (size_t)(b * SEQ + k0g) * DIM;

  auto stage = [&](int kb, int bs) {
    const unsigned char* kbase = kchunk + (size_t)kb * 32 * DIM;
    char* dst = &klds[bs * 16384];
    #pragma unroll
    for (int it = 0; it < 4; ++it) {
      int rp = w * 4 + it;             // 1 KB per slot
      gload_lds16(kbase + rp * 1024 + lane * 16, dst + rp * 1024);
    }
  };

  stage(0, 0);
  __syncthreads();

  for (int kb = 0; kb < nblk; ++kb) {
    int bs = kb & 1;
    if (kb + 1 < nblk) stage(kb + 1, bs ^ 1);   // async prefetch, other buffer
    const char* buf = &klds[bs * 16384];
    const char* krow0 = buf + ln * DIM;
    const char* krow1 = buf + (16 + ln) * DIM;

    f32x4 acc0 = {0.f, 0.f, 0.f, 0.f}, acc1 = {0.f, 0.f, 0.f, 0.f};
    #pragma unroll
    for (int kk = 0; kk < 16; ++kk) {
      int pos = (((kk * 4 + quad) ^ ln) << 3);  // swizzled 8B granule
      long b0 = *(const long*)(krow0 + pos);
      long b1 = *(const long*)(krow1 + pos);
      acc0 = __builtin_amdgcn_mfma_f32_16x16x32_fp8_fp8(af[kk], b0, acc0, 0, 0, 0);
      acc1 = __builtin_amdgcn_mfma_f32_16x16x32_fp8_fp8(af[kk], b1, acc1, 0, 0, 0);
    }

    int lk0 = kb * 32 + ln, lk1 = lk0 + 16;
    float4 V0 = V[b * SEQ + k0g + lk0];
    float4 V1 = V[b * SEQ + k0g + lk1];
    f32x2 vxx = {V0.x, V1.x}, vyy = {V0.y, V1.y}, vzz = {V0.z, V1.z};
    if (kb + 1 < nblk || !tail) {        // full tile: no masking (uniform)
      #pragma unroll
      for (int r = 0; r < 4; ++r) {
        f32x2 p2;
        p2.x = __expf(acc0[r] * RSQRT_D);
        p2.y = __expf(acc1[r] * RSQRT_D);
        l2[r] += p2;
        Ox2[r] += p2 * vxx; Oy2[r] += p2 * vyy; Oz2[r] += p2 * vzz;
      }
    } else {                             // final partial tile: mask invalid
      bool v0 = lk0 < nk, v1 = lk1 < nk;
      #pragma unroll
      for (int r = 0; r < 4; ++r) {
        f32x2 p2;
        p2.x = v0 ? __expf(acc0[r] * RSQRT_D) : 0.f;
        p2.y = v1 ? __expf(acc1[r] * RSQRT_D) : 0.f;
        l2[r] += p2;
        Ox2[r] += p2 * vxx; Oy2[r] += p2 * vyy; Oz2[r] += p2 * vzz;
      }
    }
    __syncthreads();   // waves done reading buf[bs]; prefetch drained here
  }

  // reduce over the 16 key-lanes + partial write (C: col=ln, row=quad*4+r)
  #pragma unroll
  for (int r = 0; r < 4; ++r) {
    float v0 = l2[r].x + l2[r].y;
    float v1 = Ox2[r].x + Ox2[r].y;
    float v2 = Oy2[r].x + Oy2[r].y;
    float v3 = Oz2[r].x + Oz2[r].y;
    #pragma unroll
    for (int o = 1; o < 16; o <<= 1) {
      v0 += __shfl_xor(v0, o);
      v1 += __shfl_xor(v1, o);
      v2 += __shfl_xor(v2, o);
      v3 += __shfl_xor(v3, o);
    }
    if (ln == 0) {
      int q = q0 + quad * 4 + r;
      part[((size_t)(dir * BAT + b) * 4 + chunk) * SEQ + q] =
          make_float4(v0, v1, v2, v3);
    }
  }
}

// ---------------------------------------------------------------------------
// Kernel 4: combine split-K partials.
// ---------------------------------------------------------------------------
__global__ __launch_bounds__(256) void k_attn_reduce(
    const float4* __restrict__ part, float* __restrict__ out) {
  int t = blockIdx.x * 256 + threadIdx.x;    // 0..32767
  int dir = t >> 14, rem = t & 16383, b = rem >> 11, q = rem & 2047;
  size_t base = ((size_t)(dir * BAT + b) * 4) * SEQ + q;
  float4 s0 = part[base];
  float4 s1 = part[base + SEQ];
  float4 s2 = part[base + 2 * SEQ];
  float4 s3 = part[base + 3 * SEQ];
  float inv = 1.f / (s0.x + s1.x + s2.x + s3.x);
  float* ob = out + (size_t)dir * (SEQ * BAT * 3) + ((size_t)q * BAT + b) * 3;
  ob[0] = (s0.y + s1.y + s2.y + s3.y) * inv;
  ob[1] = (s0.z + s1.z + s2.z + s3.z) * inv;
  ob[2] = (s0.w + s1.w + s2.w + s3.w) * inv;
}

// ---------------------------------------------------------------------------
extern "C" void kernel_launch(void* const* d_in, const int* in_sizes, int n_in,
                              void* d_out, int out_size, void* d_ws, size_t ws_size,
                              hipStream_t stream) {
  const float* src  = (const float*)d_in[0];
  const float* tgt  = (const float*)d_in[1];
  const float* sxyz = (const float*)d_in[2];
  const float* txyz = (const float*)d_in[3];
  const int* slens  = (const int*)d_in[4];
  const int* tlens  = (const int*)d_in[5];
  const float* Wq   = (const float*)d_in[6];
  const float* bq   = (const float*)d_in[7];
  const float* Wk   = (const float*)d_in[8];
  const float* bk   = (const float*)d_in[9];
  const float* Wc   = (const float*)d_in[10];
  const float* bc   = (const float*)d_in[11];
  float* out = (float*)d_out;

  char* ws = (char*)d_ws;
  size_t off = 0;
  auto carve = [&](size_t bytes) -> char* {
    char* p = ws + off;
    off += (bytes + 255) & ~(size_t)255;
    return p;
  };
  const size_t FEAT_BF  = (size_t)BAT * SEQ * DIM * 2;  // 16 MB bf16
  const size_t FEAT_FP8 = (size_t)BAT * SEQ * DIM;      // 8 MB fp8
  unsigned short* srcT = (unsigned short*)carve(FEAT_BF);
  unsigned short* tgtT = (unsigned short*)carve(FEAT_BF);
  unsigned char* Qsrc = (unsigned char*)carve(FEAT_FP8);
  unsigned char* Ktgt = (unsigned char*)carve(FEAT_FP8);
  unsigned char* Qtgt = (unsigned char*)carve(FEAT_FP8);
  unsigned char* Ksrc = (unsigned char*)carve(FEAT_FP8);
  unsigned short* Wqb  = (unsigned short*)carve((size_t)DIM * DIM * 2);
  unsigned short* Wkb  = (unsigned short*)carve((size_t)DIM * DIM * 2);
  float4* Vsrc = (float4*)carve((size_t)BAT * SEQ * 16);
  float4* Vtgt = (float4*)carve((size_t)BAT * SEQ * 16);
  // split-K partials (2 MB) aliased onto srcT (dead after k_proj).
  float4* part = (float4*)srcT;

  k_pack<<<dim3(4352, 2), 256, 0, stream>>>(src, tgt, Wc, bc, sxyz, txyz, Wq, Wk,
                                            srcT, tgtT, Vsrc, Vtgt, Wqb, Wkb, out);
  k_proj<<<dim3(2048), 256, 0, stream>>>(srcT, tgtT, Wqb, Wkb, bq, bk,
                                         Qsrc, Ktgt, Qtgt, Ksrc);
  k_attn<<<dim3(2048), 256, 0, stream>>>(Qsrc, Ktgt, Qtgt, Ksrc, Vsrc, Vtgt,
                                         slens, tlens, part);
  k_attn_reduce<<<dim3(128), 256, 0, stream>>>(part, out);
}

// Round 7
// 245.511 us; speedup vs baseline: 1.0808x; 1.0808x over previous
//
#include <hip/hip_runtime.h>

typedef __attribute__((ext_vector_type(8))) short short8;
typedef __attribute__((ext_vector_type(4))) float f32x4;

#define SEQ 2048
#define BAT 8
#define DIM 512
#define RSQRT_D 0.044194173824159216f  // 1/sqrt(512)

__device__ __forceinline__ unsigned short f2bf(float x) {
  union { float f; unsigned u; } v; v.f = x;
  unsigned r = (v.u + 0x7FFFu + ((v.u >> 16) & 1u)) >> 16;  // RNE
  return (unsigned short)r;
}

__device__ __forceinline__ unsigned char f2fp8(float x) {
  return (unsigned char)(__builtin_amdgcn_cvt_pk_fp8_f32(x, x, 0, false) & 0xFF);
}

// async 16B global -> LDS. lds base wave-uniform; HW adds lane*16.
__device__ __forceinline__ void gload_lds16(const void* g, void* lds_base) {
  __builtin_amdgcn_global_load_lds(
      (const __attribute__((address_space(1))) unsigned int*)g,
      (__attribute__((address_space(3))) unsigned int*)lds_base,
      16, 0, 0);
}

// ---------------------------------------------------------------------------
// Kernel 1: fused pack. blocks x<4096: transpose feats (S,B,D) f32 ->
// (B,S,D) bf16 + overlap dot (y = src/tgt). blocks >=4096: y==0 -> cast
// Wq/Wk -> bf16; y==1 -> pack xyz -> (B,S,4) f32. grid = (4352, 2).
// ---------------------------------------------------------------------------
__global__ __launch_bounds__(256) void k_pack(
    const float* __restrict__ src, const float* __restrict__ tgt,
    const float* __restrict__ Wc, const float* __restrict__ bc,
    const float* __restrict__ sxyz, const float* __restrict__ txyz,
    const float* __restrict__ Wq, const float* __restrict__ Wk,
    unsigned short* __restrict__ srcT, unsigned short* __restrict__ tgtT,
    float4* __restrict__ Vsrc, float4* __restrict__ Vtgt,
    unsigned short* __restrict__ Wqb, unsigned short* __restrict__ Wkb,
    float* __restrict__ out) {
  int which = blockIdx.y;
  if (blockIdx.x >= 4096) {
    int e = (blockIdx.x - 4096) * 256 + threadIdx.x;   // 0..65535
    if (which == 0) {
      int wsel = e >> 15, j = e & 32767;
      const float* wp = (wsel ? Wk : Wq) + (size_t)j * 8;
      unsigned short* o = wsel ? Wkb : Wqb;
      float4 f0 = *(const float4*)wp, f1 = *(const float4*)(wp + 4);
      uint4 pk;
      pk.x = (unsigned)f2bf(f0.x) | ((unsigned)f2bf(f0.y) << 16);
      pk.y = (unsigned)f2bf(f0.z) | ((unsigned)f2bf(f0.w) << 16);
      pk.z = (unsigned)f2bf(f1.x) | ((unsigned)f2bf(f1.y) << 16);
      pk.w = (unsigned)f2bf(f1.z) | ((unsigned)f2bf(f1.w) << 16);
      *(uint4*)(o + (size_t)j * 8) = pk;
    } else if (e < 32768) {
      int wsel = e >> 14, id = e & 16383;
      int s = id >> 3, b = id & 7;
      const float* xyz = (wsel ? txyz : sxyz) + (size_t)id * 3;
      float4 v = make_float4(xyz[0], xyz[1], xyz[2], 0.f);
      (wsel ? Vtgt : Vsrc)[b * SEQ + s] = v;
    }
    return;
  }
  int w = threadIdx.x >> 6, lane = threadIdx.x & 63;
  int row = blockIdx.x * 4 + w;            // row = s*B + b
  const float* in = (which ? tgt : src) + (size_t)row * DIM;
  unsigned short* T = which ? tgtT : srcT;
  int s = row >> 3, b = row & 7;

  const float4* in4 = (const float4*)in;
  float4 f0 = in4[lane * 2], f1 = in4[lane * 2 + 1];

  uint4 pk;
  pk.x = (unsigned)f2bf(f0.x) | ((unsigned)f2bf(f0.y) << 16);
  pk.y = (unsigned)f2bf(f0.z) | ((unsigned)f2bf(f0.w) << 16);
  pk.z = (unsigned)f2bf(f1.x) | ((unsigned)f2bf(f1.y) << 16);
  pk.w = (unsigned)f2bf(f1.z) | ((unsigned)f2bf(f1.w) << 16);
  *(uint4*)(T + ((size_t)(b * SEQ + s) * DIM + lane * 8)) = pk;

  const float4* wc4 = (const float4*)Wc;
  float4 w0 = wc4[lane * 2], w1 = wc4[lane * 2 + 1];
  float d = f0.x * w0.x + f0.y * w0.y + f0.z * w0.z + f0.w * w0.w +
            f1.x * w1.x + f1.y * w1.y + f1.z * w1.z + f1.w * w1.w;
  for (int o = 32; o; o >>= 1) d += __shfl_xor(d, o);
  if (lane == 0) {
    int base = which ? (SEQ * BAT * 6 + SEQ * BAT) : (SEQ * BAT * 6);
    out[base + row] = d + bc[0];
  }
}

// ---------------------------------------------------------------------------
// Kernel 2: projection GEMM, fp8-e4m3 output, UNSCALED (1/sqrt(D) in attn).
// Q linear; K with bank-free swizzle baked into the global byte layout:
//   byte (row,d) at row*512 + ((d>>3 ^ (row&15))<<3) + (d&7)
// XCD grouping: the 16 blocks (4 n x 4 z) sharing one m-tile are consecutive
// on one XCD (id%8) -> A-tile L2-fetched once per XCD; W L2-resident.
// grid = 2048 x 1D, block = 256.
// ---------------------------------------------------------------------------
__global__ __launch_bounds__(256) void k_proj(
    const unsigned short* __restrict__ srcT, const unsigned short* __restrict__ tgtT,
    const unsigned short* __restrict__ Wqb, const unsigned short* __restrict__ Wkb,
    const float* __restrict__ bq, const float* __restrict__ bk,
    unsigned char* __restrict__ Qsrc, unsigned char* __restrict__ Ktgt,
    unsigned char* __restrict__ Qtgt, unsigned char* __restrict__ Ksrc) {
  __shared__ __align__(16) char at[16384];   // 128 rows x 128B (64 bf16)
  __shared__ __align__(16) char bt[16384];
  int id = blockIdx.x;                 // 0..2047
  int x = id & 7, t = id >> 3;         // XCD = x (heuristic)
  int m = x * 16 + (t >> 4);           // 0..127, 16 consecutive blocks share m
  int inner = t & 15;
  int n = inner & 3, z = inner >> 2;
  bool isQ = (z == 0 || z == 2);
  const unsigned short* A = (z == 0 || z == 3) ? srcT : tgtT;
  const unsigned short* W = isQ ? Wqb : Wkb;
  const float* bias = isQ ? bq : bk;
  unsigned char* O = z == 0 ? Qsrc : z == 1 ? Ktgt : z == 2 ? Qtgt : Ksrc;

  int m0 = m * 128, n0 = n * 128;
  int tid = threadIdx.x, w = tid >> 6, lane = tid & 63;
  int ln = lane & 15, quad = lane >> 4;
  int moff = (w & 1) * 64, noff = (w >> 1) * 64;

  f32x4 acc[4][4];
  f32x4 zero = {0.f, 0.f, 0.f, 0.f};
  for (int mi = 0; mi < 4; ++mi)
    for (int ni = 0; ni < 4; ++ni) acc[mi][ni] = zero;

  for (int kb = 0; kb < DIM; kb += 64) {
    #pragma unroll
    for (int it = 0; it < 4; ++it) {
      int rbase = w * 32 + it * 8;
      int r = rbase + (lane >> 3);
      int c = (lane & 7) ^ (r & 7);
      gload_lds16(A + ((size_t)(m0 + r) * DIM + kb + c * 8), &at[rbase * 128]);
      gload_lds16(W + ((size_t)(n0 + r) * DIM + kb + c * 8), &bt[rbase * 128]);
    }
    __syncthreads();
    #pragma unroll
    for (int ks = 0; ks < 2; ++ks) {
      short8 afr[4], bfr[4];
      #pragma unroll
      for (int mi = 0; mi < 4; ++mi) {
        int r = moff + mi * 16 + ln;
        int p = (ks * 4 + quad) ^ (r & 7);
        afr[mi] = *(const short8*)(&at[r * 128 + p * 16]);
      }
      #pragma unroll
      for (int ni = 0; ni < 4; ++ni) {
        int r = noff + ni * 16 + ln;
        int p = (ks * 4 + quad) ^ (r & 7);
        bfr[ni] = *(const short8*)(&bt[r * 128 + p * 16]);
      }
      #pragma unroll
      for (int mi = 0; mi < 4; ++mi)
        #pragma unroll
        for (int ni = 0; ni < 4; ++ni)
          acc[mi][ni] = __builtin_amdgcn_mfma_f32_16x16x32_bf16(afr[mi], bfr[ni], acc[mi][ni], 0, 0, 0);
    }
    __syncthreads();
  }

  for (int ni = 0; ni < 4; ++ni) {
    int n_g = n0 + noff + ni * 16 + ln;
    float bv = bias[n_g];
    for (int mi = 0; mi < 4; ++mi) {
      int m_g = m0 + moff + mi * 16 + quad * 4;
      for (int r = 0; r < 4; ++r) {
        float v = acc[mi][ni][r] + bv;
        int row = m_g + r;
        size_t pos;
        if (isQ) pos = (size_t)row * DIM + n_g;
        else     pos = (size_t)row * DIM + ((((n_g >> 3) ^ (row & 15)) << 3) | (n_g & 7));
        O[pos] = f2fp8(v);
      }
    }
  }
}

// ---------------------------------------------------------------------------
// Kernel 3: flash attention = r5 known-good structure (fp8 scores, split-K x4,
// no-max softmax, V-SoA in LDS) with ONE change: single-buffered 16 KB K-tile
// (LDS 22.5 KB -> 7 blocks/CU = 28 waves; inter-block overlap hides the
// stage-drain instead of the intra-block double buffer). grid = 2048, blk 256.
// ---------------------------------------------------------------------------
__global__ __launch_bounds__(256) void k_attn(
    const unsigned char* __restrict__ Qsrc, const unsigned char* __restrict__ Ktgt,
    const unsigned char* __restrict__ Qtgt, const unsigned char* __restrict__ Ksrc,
    const float4* __restrict__ Vsrc, const float4* __restrict__ Vtgt,
    const int* __restrict__ src_lens, const int* __restrict__ tgt_lens,
    float4* __restrict__ part) {
  __shared__ __align__(16) char klds[16384];   // 32 keys x 512 B, swizzled
  __shared__ float vx[512], vy[512], vz[512];
  int id = blockIdx.x;                 // 0..2047
  int x = id & 7, j = id >> 3;         // XCD = x (heuristic)
  int group = (j >> 7) * 8 + x;        // 0..15 = dir*8+b, one XCD per group
  int dir = group >> 3, b = group & 7;
  int inner = j & 127;
  int chunk = inner >> 5, qb = inner & 31;

  const unsigned char* Q = dir ? Qtgt : Qsrc;
  const unsigned char* K = dir ? Ksrc : Ktgt;
  const float4* V = dir ? Vsrc : Vtgt;
  int len = (dir ? src_lens : tgt_lens)[b];
  int k0g = chunk * 512;
  int kend = min(len, k0g + 512);      // len >= 1792 so kend > k0g always
  int nblk = (kend - k0g + 31) >> 5;

  int tid = threadIdx.x, w = tid >> 6, lane = tid & 63;
  int ln = lane & 15, quad = lane >> 4;
  int q0 = qb * 64 + w * 16;

  // stage V chunk (512 keys) to LDS as SoA (conflict-free reads)
  for (int i = tid; i < 512; i += 256) {
    float4 vv = V[b * SEQ + k0g + i];
    vx[i] = vv.x; vy[i] = vv.y; vz[i] = vv.z;
  }

  // Q fp8 A-frags, full D: 16 x 8 B = 32 VGPRs. A[m=ln][k=quad*8+j].
  long af[16];
  {
    const unsigned char* qrow = Q + (size_t)(b * SEQ + q0 + ln) * DIM + quad * 8;
    #pragma unroll
    for (int kk = 0; kk < 16; ++kk)
      af[kk] = *(const long*)(qrow + kk * 32);
  }

  float l_r[4], Ox[4], Oy[4], Oz[4];
  #pragma unroll
  for (int r = 0; r < 4; ++r) { l_r[r] = 0.f; Ox[r] = Oy[r] = Oz[r] = 0.f; }

  const unsigned char* kchunk = K + (size_t)(b * SEQ + k0g) * DIM;

  for (int kb = 0; kb < nblk; ++kb) {
    // stage 32 keys x 512 B = 16 KB: identity copy (swizzle pre-baked in
    // global layout), wave w stages 4 KB.
    const unsigned char* kbase = kchunk + (size_t)kb * 32 * DIM;
    #pragma unroll
    for (int it = 0; it < 4; ++it) {
      int rp = w * 4 + it;             // 1 KB per slot
      gload_lds16(kbase + rp * 1024 + lane * 16, &klds[rp * 1024]);
    }
    __syncthreads();                   // stage complete (also covers V, Q ok)

    const char* krow0 = klds + ln * DIM;
    const char* krow1 = klds + (16 + ln) * DIM;

    f32x4 acc0 = {0.f, 0.f, 0.f, 0.f}, acc1 = {0.f, 0.f, 0.f, 0.f};
    #pragma unroll
    for (int kk = 0; kk < 16; ++kk) {
      int pos = (((kk * 4 + quad) ^ ln) << 3);  // swizzled 8B granule
      long b0 = *(const long*)(krow0 + pos);
      long b1 = *(const long*)(krow1 + pos);
      acc0 = __builtin_amdgcn_mfma_f32_16x16x32_fp8_fp8(af[kk], b0, acc0, 0, 0, 0);
      acc1 = __builtin_amdgcn_mfma_f32_16x16x32_fp8_fp8(af[kk], b1, acc1, 0, 0, 0);
    }

    int lk0 = kb * 32 + ln, lk1 = lk0 + 16;
    bool v0 = (k0g + lk0) < kend, v1 = (k0g + lk1) < kend;
    float Vx0 = vx[lk0], Vy0 = vy[lk0], Vz0 = vz[lk0];
    float Vx1 = vx[lk1], Vy1 = vy[lk1], Vz1 = vz[lk1];
    #pragma unroll
    for (int r = 0; r < 4; ++r) {
      float p0 = v0 ? __expf(acc0[r] * RSQRT_D) : 0.f;
      float p1 = v1 ? __expf(acc1[r] * RSQRT_D) : 0.f;
      l_r[r] += p0 + p1;
      Ox[r] += p0 * Vx0 + p1 * Vx1;
      Oy[r] += p0 * Vy0 + p1 * Vy1;
      Oz[r] += p0 * Vz0 + p1 * Vz1;
    }
    __syncthreads();                   // all waves done reading klds
  }

  // reduce over the 16 key-lanes + partial write (C: col=ln, row=quad*4+r)
  #pragma unroll
  for (int r = 0; r < 4; ++r) {
    float v0 = l_r[r], v1 = Ox[r], v2 = Oy[r], v3 = Oz[r];
    #pragma unroll
    for (int o = 1; o < 16; o <<= 1) {
      v0 += __shfl_xor(v0, o);
      v1 += __shfl_xor(v1, o);
      v2 += __shfl_xor(v2, o);
      v3 += __shfl_xor(v3, o);
    }
    if (ln == 0) {
      int q = q0 + quad * 4 + r;
      part[((size_t)(dir * BAT + b) * 4 + chunk) * SEQ + q] =
          make_float4(v0, v1, v2, v3);
    }
  }
}

// ---------------------------------------------------------------------------
// Kernel 4: combine split-K partials.
// ---------------------------------------------------------------------------
__global__ __launch_bounds__(256) void k_attn_reduce(
    const float4* __restrict__ part, float* __restrict__ out) {
  int t = blockIdx.x * 256 + threadIdx.x;    // 0..32767
  int dir = t >> 14, rem = t & 16383, b = rem >> 11, q = rem & 2047;
  size_t base = ((size_t)(dir * BAT + b) * 4) * SEQ + q;
  float4 s0 = part[base];
  float4 s1 = part[base + SEQ];
  float4 s2 = part[base + 2 * SEQ];
  float4 s3 = part[base + 3 * SEQ];
  float inv = 1.f / (s0.x + s1.x + s2.x + s3.x);
  float* ob = out + (size_t)dir * (SEQ * BAT * 3) + ((size_t)q * BAT + b) * 3;
  ob[0] = (s0.y + s1.y + s2.y + s3.y) * inv;
  ob[1] = (s0.z + s1.z + s2.z + s3.z) * inv;
  ob[2] = (s0.w + s1.w + s2.w + s3.w) * inv;
}

// ---------------------------------------------------------------------------
extern "C" void kernel_launch(void* const* d_in, const int* in_sizes, int n_in,
                              void* d_out, int out_size, void* d_ws, size_t ws_size,
                              hipStream_t stream) {
  const float* src  = (const float*)d_in[0];
  const float* tgt  = (const float*)d_in[1];
  const float* sxyz = (const float*)d_in[2];
  const float* txyz = (const float*)d_in[3];
  const int* slens  = (const int*)d_in[4];
  const int* tlens  = (const int*)d_in[5];
  const float* Wq   = (const float*)d_in[6];
  const float* bq   = (const float*)d_in[7];
  const float* Wk   = (const float*)d_in[8];
  const float* bk   = (const float*)d_in[9];
  const float* Wc   = (const float*)d_in[10];
  const float* bc   = (const float*)d_in[11];
  float* out = (float*)d_out;

  char* ws = (char*)d_ws;
  size_t off = 0;
  auto carve = [&](size_t bytes) -> char* {
    char* p = ws + off;
    off += (bytes + 255) & ~(size_t)255;
    return p;
  };
  const size_t FEAT_BF  = (size_t)BAT * SEQ * DIM * 2;  // 16 MB bf16
  const size_t FEAT_FP8 = (size_t)BAT * SEQ * DIM;      // 8 MB fp8
  unsigned short* srcT = (unsigned short*)carve(FEAT_BF);
  unsigned short* tgtT = (unsigned short*)carve(FEAT_BF);
  unsigned char* Qsrc = (unsigned char*)carve(FEAT_FP8);
  unsigned char* Ktgt = (unsigned char*)carve(FEAT_FP8);
  unsigned char* Qtgt = (unsigned char*)carve(FEAT_FP8);
  unsigned char* Ksrc = (unsigned char*)carve(FEAT_FP8);
  unsigned short* Wqb  = (unsigned short*)carve((size_t)DIM * DIM * 2);
  unsigned short* Wkb  = (unsigned short*)carve((size_t)DIM * DIM * 2);
  float4* Vsrc = (float4*)carve((size_t)BAT * SEQ * 16);
  float4* Vtgt = (float4*)carve((size_t)BAT * SEQ * 16);
  // split-K partials (2 MB) aliased onto srcT (dead after k_proj).
  float4* part = (float4*)srcT;

  k_pack<<<dim3(4352, 2), 256, 0, stream>>>(src, tgt, Wc, bc, sxyz, txyz, Wq, Wk,
                                            srcT, tgtT, Vsrc, Vtgt, Wqb, Wkb, out);
  k_proj<<<dim3(2048), 256, 0, stream>>>(srcT, tgtT, Wqb, Wkb, bq, bk,
                                         Qsrc, Ktgt, Qtgt, Ksrc);
  k_attn<<<dim3(2048), 256, 0, stream>>>(Qsrc, Ktgt, Qtgt, Ksrc, Vsrc, Vtgt,
                                         slens, tlens, part);
  k_attn_reduce<<<dim3(128), 256, 0, stream>>>(part, out);
}